// Round 8
// baseline (66.160 us; speedup 1.0000x reference)
//
#include <hip/hip_runtime.h>
#include <float.h>
#include <math.h>

#define KP 500000
#define KN 25000
#define KK 30
#define KD 128

// ---------------------------------------------------------------------------
// Fully fused GAT layer, max-occupancy edition. One 64-lane wave per row.
// Wave = four 16-lane quarters; iteration t: quarter q processes k = 4t+q.
//   - lane owns 8 columns (c = (lane&15)*8): 2x float4 from zf and zo
//   - e_k = softplus(zf[ik]·W1 + zo[ik]·W2): 4-round butterfly over 16 lanes
//   - un-normalized softmax (e in (0,~8], exp(e) <= ~3e3 -- same ratios as
//     max-subtracted ref): denom += exp(e); acc += exp(e) * zo_slice
//   - trailing padding -> dynamic trip count ceil(deg/4), deg via ballot
//   - NO explicit prefetch: rely on 8 waves/SIMD TLP (launch_bounds(256,8),
//     32-bit byte offsets keep VGPR <= 64) to hide random-gather latency
//   - final: quarter merge via xor-16 / xor-32 shuffle-adds, normalize, store.
// ---------------------------------------------------------------------------
__global__ __launch_bounds__(256, 8) void fused_gat_kernel(
    const float* __restrict__ zf, const float* __restrict__ zo,
    const int* __restrict__ scope, const float* __restrict__ W,
    float* __restrict__ out, int Nrows)
{
    const int wave = threadIdx.x >> 6;
    const int lane = threadIdx.x & 63;
    const int r = blockIdx.x * 4 + wave;
    if (r >= Nrows) return;

    const int q = lane >> 4;            // quarter 0..3
    const int c = (lane & 15) * 8;      // column base (same in all quarters)

    if (r == 0) {
        if (q == 0) {
            *(float4*)(out + c)     = make_float4(0.f, 0.f, 0.f, 0.f);
            *(float4*)(out + c + 4) = make_float4(0.f, 0.f, 0.f, 0.f);
        }
        return;
    }

    const float4 w1a = *(const float4*)(W + c);
    const float4 w1b = *(const float4*)(W + c + 4);        // W[0:128] slice
    const float4 w2a = *(const float4*)(W + KD + c);
    const float4 w2b = *(const float4*)(W + KD + c + 4);   // W[128:256] slice

    // lane k (k<30) holds this node's k-th neighbor pair index (1-based, 0=pad)
    const int idxl = (lane < KK) ? scope[(long)(r - 1) * KK + lane] : 0;

    // valid lanes are exactly 0..deg-1 (trailing padding)
    const int deg = __popcll(__ballot(idxl > 0));
    const int iters = (deg + 3) >> 2;

    const char* zfb = (const char*)zf;
    const char* zob = (const char*)zo;
    const unsigned cb = (unsigned)c * 4u;   // column byte offset

    float  denom = 0.f;
    float4 acca = make_float4(0.f, 0.f, 0.f, 0.f);
    float4 accb = make_float4(0.f, 0.f, 0.f, 0.f);

    for (int it = 0; it < iters; ++it) {
        const int k  = 4 * it + q;                    // this quarter's neighbor
        const int ik = __shfl(idxl, k, 64);           // k <= 31; lanes 30,31 pad
        const bool valid = (ik > 0);
        // 32-bit byte offset: max (500000-1)*512 + 508 < 2^32; pad -> row 0
        const unsigned off = valid ? (unsigned)(ik - 1) * 512u : 0u;

        const float4 a0 = *(const float4*)(zfb + off + cb);
        const float4 a1 = *(const float4*)(zfb + off + cb + 16);
        const float4 b0 = *(const float4*)(zob + off + cb);
        const float4 b1 = *(const float4*)(zob + off + cb + 16);

        float s = a0.x * w1a.x + a0.y * w1a.y + a0.z * w1a.z + a0.w * w1a.w
                + a1.x * w1b.x + a1.y * w1b.y + a1.z * w1b.z + a1.w * w1b.w
                + b0.x * w2a.x + b0.y * w2a.y + b0.z * w2a.z + b0.w * w2a.w
                + b1.x * w2b.x + b1.y * w2b.y + b1.z * w2b.z + b1.w * w2b.w;
        #pragma unroll
        for (int off2 = 8; off2; off2 >>= 1)
            s += __shfl_xor(s, off2, 16);             // reduce within quarter
        // stable softplus via fast intrinsics
        const float t = __expf(-fabsf(s));
        const float e = fmaxf(s, 0.f) + __logf(1.f + t);
        const float p = valid ? __expf(e) : 0.f;      // un-normalized weight
        denom += p;
        acca.x += p * b0.x; acca.y += p * b0.y;
        acca.z += p * b0.z; acca.w += p * b0.w;
        accb.x += p * b1.x; accb.y += p * b1.y;
        accb.z += p * b1.z; accb.w += p * b1.w;
    }

    // merge the four quarters (xor 16 then xor 32)
    #pragma unroll
    for (int off2 = 16; off2 <= 32; off2 <<= 1) {
        denom  += __shfl_xor(denom,  off2, 64);
        acca.x += __shfl_xor(acca.x, off2, 64);
        acca.y += __shfl_xor(acca.y, off2, 64);
        acca.z += __shfl_xor(acca.z, off2, 64);
        acca.w += __shfl_xor(acca.w, off2, 64);
        accb.x += __shfl_xor(accb.x, off2, 64);
        accb.y += __shfl_xor(accb.y, off2, 64);
        accb.z += __shfl_xor(accb.z, off2, 64);
        accb.w += __shfl_xor(accb.w, off2, 64);
    }
    const float inv = 1.f / fmaxf(denom, 1e-30f);     // deg>=1 so denom>0

    if (q == 0) {
        float4 oa, ob;
        oa.x = acca.x * inv; oa.y = acca.y * inv;
        oa.z = acca.z * inv; oa.w = acca.w * inv;
        ob.x = accb.x * inv; ob.y = accb.y * inv;
        ob.z = accb.z * inv; ob.w = accb.w * inv;
        *(float4*)(out + (long)r * KD + c)     = oa;
        *(float4*)(out + (long)r * KD + c + 4) = ob;
    }
}

extern "C" void kernel_launch(void* const* d_in, const int* in_sizes, int n_in,
                              void* d_out, int out_size, void* d_ws, size_t ws_size,
                              hipStream_t stream) {
    const float* zf    = (const float*)d_in[0];   // [P, D]
    const float* zo    = (const float*)d_in[1];   // [P, D]
    const int*   scope = (const int*)d_in[2];     // [N, K]
    const float* W     = (const float*)d_in[3];   // [2D, 1]
    float* out = (float*)d_out;                   // [(N+1), D]

    const int N = in_sizes[2] / KK;
    const int nrows = N + 1;
    const int grid = (nrows + 3) / 4;             // 4 rows (waves) per block
    fused_gat_kernel<<<grid, 256, 0, stream>>>(zf, zo, scope, W, out, nrows);
}